// Round 3
// baseline (235.674 us; speedup 1.0000x reference)
//
#include <hip/hip_runtime.h>

#define CHAR_EMB 30
#define NFILT    30
#define WLEN     40
#define TOUT     38      // WLEN - K + 1
#define OUTC     900     // CHAR_EMB * NFILT
#define WORD_EMB 100
#define RP2      42      // LDS row stride in f32x2 (42*8 = 336 B, 16B aligned)
#define WORDS    8       // words per block
#define PAIRS    4       // f32x2-packed word pairs per block

typedef float f32x2 __attribute__((ext_vector_type(2)));
typedef float f32x4 __attribute__((ext_vector_type(4)));

// Guaranteed packed fp32 math — do not rely on SLP forming <2 x float>.
__device__ __forceinline__ f32x2 pk_fma(f32x2 a, f32x2 b, f32x2 c) {
    f32x2 d;
    asm("v_pk_fma_f32 %0, %1, %2, %3" : "=v"(d) : "v"(a), "v"(b), "v"(c));
    return d;
}
__device__ __forceinline__ f32x2 pk_mul(f32x2 a, f32x2 b) {
    f32x2 d;
    asm("v_pk_mul_f32 %0, %1, %2" : "=v"(d) : "v"(a), "v"(b));
    return d;
}
__device__ __forceinline__ float max3f(float a, float b, float c) {
    float d;
    asm("v_max3_f32 %0, %1, %2, %3" : "=v"(d) : "v"(a), "v"(b), "v"(c));
    return d;
}

// gather one word-pair's char embeddings into an LDS buffer (threads 0..239)
__device__ __forceinline__ void gather_pair(const int* __restrict__ cq,
                                            f32x2* __restrict__ dst,
                                            const float* __restrict__ char_emb,
                                            int tid)
{
    for (int i = tid; i < WLEN * (CHAR_EMB / 2); i += 240) {
        const int t = i / 15;
        const int c = 2 * (i - 15 * t);
        const f32x2 a = *reinterpret_cast<const f32x2*>(char_emb + cq[t] * CHAR_EMB + c);
        const f32x2 b = *reinterpret_cast<const f32x2*>(char_emb + cq[WLEN + t] * CHAR_EMB + c);
        f32x2 v0; v0.x = a.x; v0.y = b.x;
        f32x2 v1; v1.x = a.y; v1.y = b.y;
        dst[(c    ) * RP2 + t] = v0;
        dst[(c + 1) * RP2 + t] = v1;
    }
}

// One block = 8 words = 4 f32x2-packed pairs.
// Threads 0..239: conv (group g = tid/8, filter phase j = tid%8).
// Threads 240..255: glove copies for all 8 words (batched loads, one latency).
// Per-pair pipeline: issue pair q+1's gather loads (regs) BEFORE conv(q);
// after conv, write regs -> other LDS buffer, ONE barrier, next pair.
// Weights loaded once per block (amortized over 8 words).
__global__ __launch_bounds__(256, 4) void encoder_kernel(
    const int*   __restrict__ char_ids,   // [BS, 40]
    const int*   __restrict__ word_ids,   // [BS]
    const float* __restrict__ char_emb,   // [102, 30]
    const float* __restrict__ conv_w,     // [900, 1, 3]
    const float* __restrict__ conv_b,     // [900]
    const float* __restrict__ glove,      // [400002, 100]
    float*       __restrict__ out,        // [BS, 1000]
    int BS)
{
    const int nbase = WORDS * (int)blockIdx.x;
    const int tid   = threadIdx.x;

    __shared__ int cid[WORDS * WLEN];                       // 320 ints
    __shared__ __align__(16) f32x2 xs[2][CHAR_EMB * RP2];   // double buffer

    // stage all 8 words' char ids: 320 consecutive ints, coalesced
    for (int i = tid; i < WORDS * WLEN; i += 256) {
        const int w = i / WLEN;
        cid[i] = (nbase + w < BS) ? char_ids[(long)nbase * WLEN + i] : 0;
    }
    __syncthreads();

    if (tid < 240) {
        // gather pair 0 directly into xs[0]
        gather_pair(&cid[0], xs[0], char_emb, tid);
    } else {
        // glove rows for all 8 words: batch ALL loads first (independent,
        // single HBM latency exposure), then store. Overlaps conv phase.
        const int k = tid - 240;
        f32x4 gv[13];
        #pragma unroll
        for (int s = 0; s < 13; ++s) {
            const int i = k + 16 * s;
            if (i < WORDS * 25) {
                const int w = i / 25, ch = i - 25 * w;
                if (nbase + w < BS)
                    gv[s] = reinterpret_cast<const f32x4*>(
                        glove + (long)word_ids[nbase + w] * WORD_EMB)[ch];
            }
        }
        #pragma unroll
        for (int s = 0; s < 13; ++s) {
            const int i = k + 16 * s;
            if (i < WORDS * 25) {
                const int w = i / 25, ch = i - 25 * w;
                if (nbase + w < BS)
                    reinterpret_cast<f32x4*>(
                        out + (long)(nbase + w) * (OUTC + WORD_EMB) + OUTC)[ch] = gv[s];
            }
        }
    }

    // weights + bias once per block (4 filter slots; zeros for invalid)
    const int g = tid >> 3;        // group / input channel 0..29
    const int j = tid & 7;         // filter phase 0..7
    f32x2 W0[4], W1[4], W2[4];
    float bias[4];
    if (tid < 240) {
        #pragma unroll
        for (int u = 0; u < 4; ++u) {
            const int f = j + 8 * u;
            float w0 = 0.f, w1 = 0.f, w2 = 0.f, bb = 0.f;
            if (f < NFILT) {
                const int o = g * NFILT + f;
                w0 = conv_w[o * 3 + 0];
                w1 = conv_w[o * 3 + 1];
                w2 = conv_w[o * 3 + 2];
                bb = conv_b[o];
            }
            W0[u].x = w0; W0[u].y = w0;
            W1[u].x = w1; W1[u].y = w1;
            W2[u].x = w2; W2[u].y = w2;
            bias[u] = bb;
        }
    }
    __syncthreads();   // xs[0] gather complete

    #pragma unroll 1
    for (int q = 0; q < PAIRS; ++q) {
        // ---- prefetch pair q+1 gather loads into registers (no wait) ----
        // 600 items over 240 threads: s0 always, s1 always, s2 iff tid<120.
        f32x2 pa0, pb0, pa1, pb1, pa2, pb2;
        int t0 = 0, c0 = 0, t1 = 0, c1 = 0, t2 = 0, c2 = 0;
        const bool pf = (q < PAIRS - 1) && (tid < 240);
        if (pf) {
            const int* cq = &cid[(q + 1) * 2 * WLEN];
            {
                const int i = tid;
                t0 = i / 15; c0 = 2 * (i - 15 * t0);
                pa0 = *reinterpret_cast<const f32x2*>(char_emb + cq[t0] * CHAR_EMB + c0);
                pb0 = *reinterpret_cast<const f32x2*>(char_emb + cq[WLEN + t0] * CHAR_EMB + c0);
            }
            {
                const int i = tid + 240;
                t1 = i / 15; c1 = 2 * (i - 15 * t1);
                pa1 = *reinterpret_cast<const f32x2*>(char_emb + cq[t1] * CHAR_EMB + c1);
                pb1 = *reinterpret_cast<const f32x2*>(char_emb + cq[WLEN + t1] * CHAR_EMB + c1);
            }
            {
                const int i = (tid < 120) ? tid + 480 : tid;  // safe redundant load
                t2 = i / 15; c2 = 2 * (i - 15 * t2);
                pa2 = *reinterpret_cast<const f32x2*>(char_emb + cq[t2] * CHAR_EMB + c2);
                pb2 = *reinterpret_cast<const f32x2*>(char_emb + cq[WLEN + t2] * CHAR_EMB + c2);
            }
        }

        // ---- conv on xs[q & 1] (hides the prefetch loads) ----
        if (tid < 240) {
            f32x2 m[4];
            #pragma unroll
            for (int u = 0; u < 4; ++u) { m[u].x = -3.4e38f; m[u].y = -3.4e38f; }

            const f32x4* rp = reinterpret_cast<const f32x4*>(&xs[q & 1][g * RP2]);
            f32x4 cur = rp[0];
            #pragma unroll 2
            for (int k = 0; k < 19; ++k) {
                const f32x4 nxt = rp[k + 1];
                const f32x2 x0 = cur.xy;   // pos 2k
                const f32x2 x1 = cur.zw;   // pos 2k+1
                const f32x2 x2 = nxt.xy;   // pos 2k+2
                const f32x2 x3 = nxt.zw;   // pos 2k+3
                #pragma unroll
                for (int u = 0; u < 4; ++u) {
                    const f32x2 v0 = pk_fma(W0[u], x0, pk_fma(W1[u], x1, pk_mul(W2[u], x2)));
                    const f32x2 v1 = pk_fma(W0[u], x1, pk_fma(W1[u], x2, pk_mul(W2[u], x3)));
                    m[u].x = max3f(m[u].x, v0.x, v1.x);
                    m[u].y = max3f(m[u].y, v0.y, v1.y);
                }
                cur = nxt;
            }

            const int wA = nbase + 2 * q;
            const int wB = wA + 1;
            float* orowA = out + (long)wA * (OUTC + WORD_EMB);
            float* orowB = out + (long)wB * (OUTC + WORD_EMB);
            #pragma unroll
            for (int u = 0; u < 4; ++u) {
                const int f = j + 8 * u;
                if (f < NFILT) {
                    const int o = g * NFILT + f;
                    const float bb = bias[u];
                    if (wA < BS) orowA[o] = m[u].x + bb;
                    if (wB < BS) orowB[o] = m[u].y + bb;
                }
            }
        }

        // ---- write prefetched pair q+1 into the other LDS buffer ----
        if (q < PAIRS - 1) {
            // conv(q-1) readers of xs[(q+1)&1] were separated by the previous
            // iteration's barrier; only one barrier per pair is required.
            if (pf) {
                f32x2* dst = xs[(q + 1) & 1];
                { f32x2 v0; v0.x = pa0.x; v0.y = pb0.x;
                  f32x2 v1; v1.x = pa0.y; v1.y = pb0.y;
                  dst[(c0    ) * RP2 + t0] = v0;
                  dst[(c0 + 1) * RP2 + t0] = v1; }
                { f32x2 v0; v0.x = pa1.x; v0.y = pb1.x;
                  f32x2 v1; v1.x = pa1.y; v1.y = pb1.y;
                  dst[(c1    ) * RP2 + t1] = v0;
                  dst[(c1 + 1) * RP2 + t1] = v1; }
                if (tid < 120) {
                  f32x2 v0; v0.x = pa2.x; v0.y = pb2.x;
                  f32x2 v1; v1.x = pa2.y; v1.y = pb2.y;
                  dst[(c2    ) * RP2 + t2] = v0;
                  dst[(c2 + 1) * RP2 + t2] = v1; }
            }
            __syncthreads();
        }
    }
}

extern "C" void kernel_launch(void* const* d_in, const int* in_sizes, int n_in,
                              void* d_out, int out_size, void* d_ws, size_t ws_size,
                              hipStream_t stream) {
    const int*   char_ids = (const int*)  d_in[0];
    const int*   word_ids = (const int*)  d_in[1];
    const float* char_emb = (const float*)d_in[2];
    const float* conv_w   = (const float*)d_in[3];
    const float* conv_b   = (const float*)d_in[4];
    const float* glove    = (const float*)d_in[5];
    float*       out      = (float*)      d_out;

    const int BS = in_sizes[1];          // 8192 words
    const int nblk = (BS + WORDS - 1) / WORDS;

    encoder_kernel<<<nblk, 256, 0, stream>>>(
        char_ids, word_ids, char_emb, conv_w, conv_b, glove, out, BS);
}

// Round 4
// 227.774 us; speedup vs baseline: 1.0347x; 1.0347x over previous
//
#include <hip/hip_runtime.h>

#define CHAR_EMB 30
#define NFILT    30
#define WLEN     40
#define TOUT     38      // WLEN - K + 1
#define OUTC     900     // CHAR_EMB * NFILT
#define WORD_EMB 100
#define RP2      42      // LDS row stride in f32x2 (42*8 = 336 B, 16B aligned)

typedef float f32x2 __attribute__((ext_vector_type(2)));
typedef float f32x4 __attribute__((ext_vector_type(4)));

// Guaranteed packed fp32 math — do not rely on SLP forming <2 x float>.
__device__ __forceinline__ f32x2 pk_fma(f32x2 a, f32x2 b, f32x2 c) {
    f32x2 d;
    asm("v_pk_fma_f32 %0, %1, %2, %3" : "=v"(d) : "v"(a), "v"(b), "v"(c));
    return d;
}
__device__ __forceinline__ f32x2 pk_mul(f32x2 a, f32x2 b) {
    f32x2 d;
    asm("v_pk_mul_f32 %0, %1, %2" : "=v"(d) : "v"(a), "v"(b));
    return d;
}
__device__ __forceinline__ float max3f(float a, float b, float c) {
    float d;
    asm("v_max3_f32 %0, %1, %2, %3" : "=v"(d) : "v"(a), "v"(b), "v"(c));
    return d;
}

// One block = TWO consecutive words packed in the two lanes of f32x2.
// Round-2 structure (best measured: 228.25 us) minus the cid LDS staging:
// the gather reads char_ids directly (15 lanes share each cid[t] -> HW
// broadcast-coalesced, 320 B L1-resident), removing one of two barriers
// and shortening the dependency chain global->LDS->barrier->LDS->global
// to global->global. Weights are loaded before the remaining barrier so
// they overlap the gather drain.
__global__ __launch_bounds__(256, 8) void encoder_kernel(
    const int*   __restrict__ char_ids,   // [BS, 40]
    const int*   __restrict__ word_ids,   // [BS]
    const float* __restrict__ char_emb,   // [102, 30]
    const float* __restrict__ conv_w,     // [900, 1, 3]
    const float* __restrict__ conv_b,     // [900]
    const float* __restrict__ glove,      // [400002, 100]
    float*       __restrict__ out,        // [BS, 1000]
    int BS)
{
    const int nA   = 2 * blockIdx.x;
    const int nB   = nA + 1;
    const bool hasB = (nB < BS);
    const int tid  = threadIdx.x;

    __shared__ __align__(16) f32x2 xs[CHAR_EMB * RP2];  // xs[c*RP2+t] = {xA[c][t], xB[c][t]}

    float* orowA = out + (long)nA * (OUTC + WORD_EMB);
    float* orowB = out + (long)nB * (OUTC + WORD_EMB);

    const int* cidA = char_ids + (long)nA * WLEN;
    const int* cidB = char_ids + (long)(hasB ? nB : nA) * WLEN;

    // gather char embeddings, float2 over channel pairs:
    // 600 items = 40 positions x 15 channel-pairs; each item loads f32x2
    // from word A's row and word B's row, writes two LDS f32x2 entries.
    // char_ids read directly: lanes with equal t broadcast from one address.
    for (int i = tid; i < WLEN * (CHAR_EMB / 2); i += 256) {
        const int t = i / 15;
        const int c = 2 * (i - 15 * t);
        const f32x2 a = *reinterpret_cast<const f32x2*>(char_emb + cidA[t] * CHAR_EMB + c);
        const f32x2 b = *reinterpret_cast<const f32x2*>(char_emb + cidB[t] * CHAR_EMB + c);
        f32x2 v0; v0.x = a.x; v0.y = b.x;
        f32x2 v1; v1.x = a.y; v1.y = b.y;
        xs[(c    ) * RP2 + t] = v0;
        xs[(c + 1) * RP2 + t] = v1;
    }

    // weights + bias (independent of xs; overlaps the gather drain)
    const int g = tid >> 3;        // group / input channel 0..29
    const int j = tid & 7;         // filter phase 0..7
    f32x2 W0[4], W1[4], W2[4];
    float bias[4];
    if (tid < 240) {
        #pragma unroll
        for (int u = 0; u < 4; ++u) {
            const int f = j + 8 * u;
            float w0 = 0.f, w1 = 0.f, w2 = 0.f, bb = 0.f;
            if (f < NFILT) {
                const int o = g * NFILT + f;
                w0 = conv_w[o * 3 + 0];
                w1 = conv_w[o * 3 + 1];
                w2 = conv_w[o * 3 + 2];
                bb = conv_b[o];
            }
            W0[u].x = w0; W0[u].y = w0;
            W1[u].x = w1; W1[u].y = w1;
            W2[u].x = w2; W2[u].y = w2;
            bias[u] = bb;
        }
    }
    __syncthreads();   // xs complete

    if (tid < 240) {
        f32x2 m[4];
        #pragma unroll
        for (int u = 0; u < 4; ++u) { m[u].x = -3.4e38f; m[u].y = -3.4e38f; }

        // rolling-window stream over the row: rp[k] = {x[2k], x[2k+1]} (A,B packed)
        const f32x4* rp = reinterpret_cast<const f32x4*>(&xs[g * RP2]);
        f32x4 cur = rp[0];
        #pragma unroll 2
        for (int k = 0; k < 19; ++k) {
            const f32x4 nxt = rp[k + 1];
            const f32x2 x0 = cur.xy;   // pos 2k
            const f32x2 x1 = cur.zw;   // pos 2k+1
            const f32x2 x2 = nxt.xy;   // pos 2k+2
            const f32x2 x3 = nxt.zw;   // pos 2k+3
            #pragma unroll
            for (int u = 0; u < 4; ++u) {
                const f32x2 v0 = pk_fma(W0[u], x0, pk_fma(W1[u], x1, pk_mul(W2[u], x2)));
                const f32x2 v1 = pk_fma(W0[u], x1, pk_fma(W1[u], x2, pk_mul(W2[u], x3)));
                m[u].x = max3f(m[u].x, v0.x, v1.x);
                m[u].y = max3f(m[u].y, v0.y, v1.y);
            }
            cur = nxt;
        }

        #pragma unroll
        for (int u = 0; u < 4; ++u) {
            const int f = j + 8 * u;
            if (f < NFILT) {
                const int o = g * NFILT + f;
                const float bb = bias[u];
                orowA[o] = m[u].x + bb;
                if (hasB) orowB[o] = m[u].y + bb;
            }
        }
    } else {
        // threads 240..255: glove row copies, overlapped with conv
        const int k = tid - 240;
        {
            const f32x4* gp = reinterpret_cast<const f32x4*>(glove + (long)word_ids[nA] * WORD_EMB);
            f32x4* op = reinterpret_cast<f32x4*>(orowA + OUTC);
            #pragma unroll
            for (int q = 0; q < 2; ++q) {
                const int idx = k + 16 * q;
                if (idx < WORD_EMB / 4) op[idx] = gp[idx];
            }
        }
        if (hasB) {
            const f32x4* gp = reinterpret_cast<const f32x4*>(glove + (long)word_ids[nB] * WORD_EMB);
            f32x4* op = reinterpret_cast<f32x4*>(orowB + OUTC);
            #pragma unroll
            for (int q = 0; q < 2; ++q) {
                const int idx = k + 16 * q;
                if (idx < WORD_EMB / 4) op[idx] = gp[idx];
            }
        }
    }
}

extern "C" void kernel_launch(void* const* d_in, const int* in_sizes, int n_in,
                              void* d_out, int out_size, void* d_ws, size_t ws_size,
                              hipStream_t stream) {
    const int*   char_ids = (const int*)  d_in[0];
    const int*   word_ids = (const int*)  d_in[1];
    const float* char_emb = (const float*)d_in[2];
    const float* conv_w   = (const float*)d_in[3];
    const float* conv_b   = (const float*)d_in[4];
    const float* glove    = (const float*)d_in[5];
    float*       out      = (float*)      d_out;

    const int BS = in_sizes[1];          // 8192 words
    const int nblk = (BS + 1) / 2;

    encoder_kernel<<<nblk, 256, 0, stream>>>(
        char_ids, word_ids, char_emb, conv_w, conv_b, glove, out, BS);
}